// Round 14
// baseline (165.914 us; speedup 1.0000x reference)
//
#include <hip/hip_runtime.h>
#include <hip/hip_bf16.h>
#include <string.h>

// CrossOp via bf16 MFMA (32x32x16) implicit-GEMM, 2-row band + co-split.
// Block = (b, hb, co-half): 2 output rows x 128 px x 32 co. Grid 512 = 2/CU.
// 512 threads = 8 waves: wave w -> hh = w&1 (row), wq = w>>1 (32-px quad).
// Per iteration the block writes 1 KB CONTIGUOUS per co-plane (2 adjacent
// rows x 128 px, waves barrier-synced) - round-13's DRAM-page win - while
// 2 blocks/CU restores cross-block overlap at barriers (round-10's win).
// Pipeline: write-then-reissue depth-2, counted vmcnt (NT stores never
// drained in-loop), lgkm-only barrier. LDS: y dbuf 2x[4 rows][130][16ci->24]
// + static x tile = 74.9 KB/block.

typedef __attribute__((ext_vector_type(8))) short short8;
typedef __attribute__((ext_vector_type(16))) float f32x16;
typedef __attribute__((ext_vector_type(4))) unsigned int u32x4;

#define NEG_SLOPE 0.01f

constexpr int CIP    = 24;             // shorts per (row,col) ci slab (48 B)
constexpr int COLS   = 130;            // 128 + 2 halo (halo cols stay zero)
constexpr int ROWP   = COLS * CIP;     // 3120 shorts
constexpr int TILESH = 4 * ROWP;       // 12480 shorts = 24.96 KB per tile

__device__ __forceinline__ short to_bf16s(float f) {
    unsigned u = __builtin_bit_cast(unsigned, f);
    u += 0x7fffu + ((u >> 16) & 1u);   // RNE
    return (short)(u >> 16);
}

__device__ __forceinline__ unsigned pack2(float a, float b) {
    __hip_bfloat162 t = __float22bfloat162_rn(float2{a, b});   // v_cvt_pk_bf16_f32
    unsigned u;
    memcpy(&u, &t, sizeof(u));
    return u;
}

__global__ __launch_bounds__(512, 4)
void crossop_v5(const float* __restrict__ xp, const float* __restrict__ yp,
                const float* __restrict__ wp, const float* __restrict__ bp,
                float* __restrict__ out)
{
    __shared__ __align__(16) short st[3][TILESH];   // [0],[1]=y dbuf, [2]=x static

    const int bid  = blockIdx.x;           // 0..511
    const int xcd  = bid & 7;              // fixed (b, co-half) per XCD
    const int hb   = bid >> 3;             // 0..63 (2-row band)
    const int b    = xcd >> 1;
    const int cob  = xcd & 1;
    const int h0   = hb * 2;

    const int tid  = threadIdx.x;
    const int lane = tid & 63;
    const int wid  = tid >> 6;             // 0..7
    const int l31  = lane & 31;
    const int hi   = lane >> 5;            // k-half / +4 co rows
    const int co0w = cob << 5;             // block's co base (0 or 32)
    const int hh   = wid & 1;              // which of the 2 output rows
    const int wq   = wid >> 1;             // w-quad (0..3), 32 px

    float* ntgt  = out;
    float* inter = out + (size_t)4 * 64 * 16384;
    const float* ybase = yp + (size_t)b * 32 * 16 * 16384;

    // ---------------- zero LDS once (halo cols / OOB rows stay 0) ---------
    {
        u32x4 zz = {0, 0, 0, 0};
        u32x4* z = (u32x4*)&st[0][0];
        for (int i = tid; i < (3 * TILESH * 2) / 16; i += 512) z[i] = zz;
    }

    // ---------------- staging: 512 threads, 16 values each -----------------
    const int  wv   = tid & 127;           // input col; tile col wv+1
    const int  rr   = tid >> 7;            // tile row 0..3 (input row h0-1+rr)
    const int  hin  = h0 - 1 + rr;
    const bool sval = (unsigned)hin < 128u;
    float sr[16];

#define STAGE_ISSUE(SRC) do {                                                 \
    const float* p = (SRC) + (ptrdiff_t)hin * 128 + wv;                       \
    _Pragma("unroll")                                                         \
    for (int c = 0; c < 16; ++c)                                              \
        sr[c] = sval ? p[(ptrdiff_t)c * 16384] : 0.f;                         \
    } while (0)

#define STAGE_WRITE(BUF) do { if (sval) {                                     \
    u32x4 v0, v1;                                                             \
    _Pragma("unroll")                                                         \
    for (int c2 = 0; c2 < 4; ++c2) {                                          \
        v0[c2] = pack2(sr[2 * c2],     sr[2 * c2 + 1]);                       \
        v1[c2] = pack2(sr[8 + 2 * c2], sr[8 + 2 * c2 + 1]);                   \
    }                                                                         \
    *(u32x4*)&(BUF)[rr * ROWP + (wv + 1) * CIP + 0] = v0;                     \
    *(u32x4*)&(BUF)[rr * ROWP + (wv + 1) * CIP + 8] = v1;                     \
    } } while (0)

    // ---------------- persistent wy fragments (9 x short8 = 36 VGPR) ------
    short8 wy[9];
    #pragma unroll
    for (int sh = 0; sh < 9; ++sh) {
        #pragma unroll
        for (int j = 0; j < 8; ++j) {
            int ci = hi * 8 + j;           // k = (lane>>5)*8 + j within k-step
            wy[sh][j] = to_bf16s(wp[((co0w + l31) * 32 + 16 + ci) * 9 + sh]);
        }
    }

    // per-lane B column base; MFMA row offset = (sh/3 + hh)*ROWP
    const int cb = (wq * 32 + l31) * CIP + hi * 8;

    // ---------------- prologue: x -> st[2]; ox = conv_x + bias -------------
    STAGE_ISSUE(xp + (size_t)b * 16 * 16384);
    STAGE_WRITE(st[2]);
    __syncthreads();

    f32x16 ox;
    #pragma unroll
    for (int r = 0; r < 16; ++r)
        ox[r] = bp[co0w + (r & 3) + 8 * (r >> 2) + 4 * hi];
    {
        const short* sb = st[2];
        #pragma unroll
        for (int sh = 0; sh < 9; ++sh) {
            short8 ax;
            #pragma unroll
            for (int j = 0; j < 8; ++j) {
                int ci = hi * 8 + j;
                ax[j] = to_bf16s(wp[((co0w + l31) * 32 + ci) * 9 + sh]);
            }
            const int off = (sh / 3 + hh) * ROWP + (sh % 3) * CIP;
            ox = __builtin_amdgcn_mfma_f32_32x32x16_bf16(ax, *(const short8*)&sb[cb + off], ox, 0, 0, 0);
        }
    }

    // y0 -> st[1] (full-latency, prologue only), then prefetch y1 -> sr
    STAGE_ISSUE(ybase + (size_t)0 * 16 * 16384);
    STAGE_WRITE(st[1]);
    STAGE_ISSUE(ybase + (size_t)1 * 16 * 16384);
    __syncthreads();

    // ---------------- s-loop: write-then-reissue depth-2 pipeline ----------
    f32x16 ms;
    #pragma unroll
    for (int r = 0; r < 16; ++r) ms[r] = 0.f;

    for (int s = 0; s < 32; ++s) {
        // 1) ds_write sr (= y(s+1)): counted vmcnt, NT stores stay in flight
        if (s + 1 < 32) STAGE_WRITE(st[s & 1]);

        // 2) reissue the SAME sr registers with y(s+2) loads
        if (s + 2 < 32) STAGE_ISSUE(ybase + (size_t)(s + 2) * 16 * 16384);

        // 3) MFMA phase on y_s (st[(s+1)&1])
        const short* sb = st[(s + 1) & 1];
        f32x16 acc = ox;
        #pragma unroll
        for (int sh = 0; sh < 9; ++sh) {
            const int off = (sh / 3 + hh) * ROWP + (sh % 3) * CIP;
            acc = __builtin_amdgcn_mfma_f32_32x32x16_bf16(wy[sh], *(const short8*)&sb[cb + off], acc, 0, 0, 0);
        }

        // 4) leaky + NT stores: 1 KB contiguous per co-plane per block-iter
        {
            float* p0 = inter + ((size_t)(b * 32 + s) * 64 + co0w + 4 * hi) * 16384
                      + (size_t)(h0 + hh) * 128 + wq * 32 + l31;
            #pragma unroll
            for (int r = 0; r < 16; ++r) {
                float v = acc[r];
                v = v >= 0.f ? v : NEG_SLOPE * v;
                __builtin_nontemporal_store(v, p0 + (ptrdiff_t)((r & 3) + 8 * (r >> 2)) * 16384);
                ms[r] += v;
            }
        }

        // 5) LDS-only barrier
        asm volatile("s_waitcnt lgkmcnt(0)" ::: "memory");
        __builtin_amdgcn_s_barrier();
        asm volatile("" ::: "memory");
    }

    // ---------------- mean over Sy ----------------------------------------
    {
        float* p0 = ntgt + ((size_t)b * 64 + co0w + 4 * hi) * 16384
                  + (size_t)(h0 + hh) * 128 + wq * 32 + l31;
        #pragma unroll
        for (int r = 0; r < 16; ++r)
            __builtin_nontemporal_store(ms[r] * 0.03125f,
                                        p0 + (ptrdiff_t)((r & 3) + 8 * (r >> 2)) * 16384);
    }
#undef STAGE_ISSUE
#undef STAGE_WRITE
}

extern "C" void kernel_launch(void* const* d_in, const int* in_sizes, int n_in,
                              void* d_out, int out_size, void* d_ws, size_t ws_size,
                              hipStream_t stream) {
    const float* x    = (const float*)d_in[0];
    const float* y    = (const float*)d_in[1];
    const float* wgt  = (const float*)d_in[2];
    const float* bias = (const float*)d_in[3];
    float* out = (float*)d_out;

    crossop_v5<<<512, 512, 0, stream>>>(x, y, wgt, bias, out);
}